// Round 5
// baseline (526.238 us; speedup 1.0000x reference)
//
#include <hip/hip_runtime.h>
#include <hip/hip_bf16.h>

// ---------- CSR build ----------
__global__ void k_hist(const int* __restrict__ dst, int* __restrict__ cnt, int E) {
    int e = blockIdx.x * blockDim.x + threadIdx.x;
    if (e < E) atomicAdd(&cnt[dst[e]], 1);
}

__global__ void k_scanA(const int* __restrict__ cnt, int* __restrict__ bsum, int N) {
    __shared__ int sh[256];
    int i = blockIdx.x * 256 + threadIdx.x;
    sh[threadIdx.x] = (i < N) ? cnt[i] : 0;
    __syncthreads();
    for (int off = 128; off > 0; off >>= 1) {
        if (threadIdx.x < off) sh[threadIdx.x] += sh[threadIdx.x + off];
        __syncthreads();
    }
    if (threadIdx.x == 0) bsum[blockIdx.x] = sh[0];
}

__global__ void k_scanB(int* __restrict__ bsum, int nb) {
    __shared__ int sh[1024];
    int t = threadIdx.x;
    sh[t] = (t < nb) ? bsum[t] : 0;
    __syncthreads();
    for (int off = 1; off < 1024; off <<= 1) {
        int v = (t >= off) ? sh[t - off] : 0;
        __syncthreads();
        sh[t] += v;
        __syncthreads();
    }
    if (t < nb) bsum[t] = (t == 0) ? 0 : sh[t - 1];
}

__global__ void k_scanC(const int* __restrict__ cnt, const int* __restrict__ boff,
                        int* __restrict__ row_ptr, float* __restrict__ dis, int N) {
    __shared__ int sh[256];
    int i = blockIdx.x * 256 + threadIdx.x;
    int v = (i < N) ? cnt[i] : 0;
    sh[threadIdx.x] = v;
    __syncthreads();
    for (int off = 1; off < 256; off <<= 1) {
        int u = (threadIdx.x >= off) ? sh[threadIdx.x - off] : 0;
        __syncthreads();
        sh[threadIdx.x] += u;
        __syncthreads();
    }
    if (i < N) {
        row_ptr[i] = sh[threadIdx.x] - v + boff[blockIdx.x];
        dis[i] = rsqrtf((float)v + 1.0f);
    }
}

__global__ void k_fill(const int* __restrict__ src, const int* __restrict__ dst,
                       const int* __restrict__ row_ptr, int* __restrict__ cursor,
                       int* __restrict__ csr_src, int E) {
    int e = blockIdx.x * blockDim.x + threadIdx.x;
    if (e < E) {
        int d = dst[e];
        int pos = row_ptr[d] + atomicAdd(&cursor[d], 1);
        csr_src[pos] = src[e];
    }
}

// ---------- row-looped GEMM with optional fused BN/ReLU/residual on the input ----------
// MODE 0: a = in (raw)
// MODE 1: a = relu(bnB(in))
// MODE 2: a = relu(bnB(in) + relu(bnA(in2)))
// out[row] = (a[row] @ W) * dis[row]
template <int K, int MODE>
__global__ void __launch_bounds__(256) k_gemm_f(const float* __restrict__ in,
                                                const float* __restrict__ in2,
                                                const float* __restrict__ W,
                                                const float* __restrict__ dis,
                                                const float* __restrict__ statsB,
                                                const float* __restrict__ gB,
                                                const float* __restrict__ beB,
                                                const float* __restrict__ statsA,
                                                const float* __restrict__ gA,
                                                const float* __restrict__ beA,
                                                float* __restrict__ out,
                                                float invN, int N) {
    __shared__ float Wl[K * 64];
    __shared__ float scB[64], shB[64], scA[64], shA[64];
    if (MODE >= 1 && threadIdx.x < 64) {
        int c = threadIdx.x;
        float mu  = statsB[c] * invN;
        float var = statsB[64 + c] * invN - mu * mu;
        float s   = gB[c] * rsqrtf(var + 1e-5f);
        scB[c] = s; shB[c] = beB[c] - mu * s;
    }
    if (MODE == 2 && threadIdx.x >= 64 && threadIdx.x < 128) {
        int c = threadIdx.x - 64;
        float mu  = statsA[c] * invN;
        float var = statsA[64 + c] * invN - mu * mu;
        float s   = gA[c] * rsqrtf(var + 1e-5f);
        scA[c] = s; shA[c] = beA[c] - mu * s;
    }
    for (int i = threadIdx.x; i < K * 16; i += 256)
        ((float4*)Wl)[i] = ((const float4*)W)[i];
    __syncthreads();
    int lane = threadIdx.x & 63;
    int wid  = blockIdx.x * 4 + (threadIdx.x >> 6);
    int nw   = gridDim.x * 4;
    int ngrp = (N + 3) >> 2;
    for (int g = wid; g < ngrp; g += nw) {
        int base = g * 4;
        int r1 = min(base + 1, N - 1), r2 = min(base + 2, N - 1), r3 = min(base + 3, N - 1);
        const float4* p0 = (const float4*)(in + (size_t)base * K);
        const float4* p1 = (const float4*)(in + (size_t)r1 * K);
        const float4* p2 = (const float4*)(in + (size_t)r2 * K);
        const float4* p3 = (const float4*)(in + (size_t)r3 * K);
        const float4* q0 = (const float4*)(in2 + (size_t)base * K);
        const float4* q1 = (const float4*)(in2 + (size_t)r1 * K);
        const float4* q2 = (const float4*)(in2 + (size_t)r2 * K);
        const float4* q3 = (const float4*)(in2 + (size_t)r3 * K);
        float acc0 = 0.f, acc1 = 0.f, acc2 = 0.f, acc3 = 0.f;
#pragma unroll 4
        for (int kg = 0; kg < K / 4; ++kg) {
            float4 a0 = p0[kg], a1 = p1[kg], a2 = p2[kg], a3 = p3[kg];
            if (MODE >= 1) {
                float4 sc = ((const float4*)scB)[kg];
                float4 sh = ((const float4*)shB)[kg];
                a0.x = a0.x * sc.x + sh.x; a0.y = a0.y * sc.y + sh.y; a0.z = a0.z * sc.z + sh.z; a0.w = a0.w * sc.w + sh.w;
                a1.x = a1.x * sc.x + sh.x; a1.y = a1.y * sc.y + sh.y; a1.z = a1.z * sc.z + sh.z; a1.w = a1.w * sc.w + sh.w;
                a2.x = a2.x * sc.x + sh.x; a2.y = a2.y * sc.y + sh.y; a2.z = a2.z * sc.z + sh.z; a2.w = a2.w * sc.w + sh.w;
                a3.x = a3.x * sc.x + sh.x; a3.y = a3.y * sc.y + sh.y; a3.z = a3.z * sc.z + sh.z; a3.w = a3.w * sc.w + sh.w;
                if (MODE == 2) {
                    float4 u0 = q0[kg], u1 = q1[kg], u2 = q2[kg], u3 = q3[kg];
                    float4 sa = ((const float4*)scA)[kg];
                    float4 ha = ((const float4*)shA)[kg];
                    a0.x += fmaxf(u0.x * sa.x + ha.x, 0.f); a0.y += fmaxf(u0.y * sa.y + ha.y, 0.f);
                    a0.z += fmaxf(u0.z * sa.z + ha.z, 0.f); a0.w += fmaxf(u0.w * sa.w + ha.w, 0.f);
                    a1.x += fmaxf(u1.x * sa.x + ha.x, 0.f); a1.y += fmaxf(u1.y * sa.y + ha.y, 0.f);
                    a1.z += fmaxf(u1.z * sa.z + ha.z, 0.f); a1.w += fmaxf(u1.w * sa.w + ha.w, 0.f);
                    a2.x += fmaxf(u2.x * sa.x + ha.x, 0.f); a2.y += fmaxf(u2.y * sa.y + ha.y, 0.f);
                    a2.z += fmaxf(u2.z * sa.z + ha.z, 0.f); a2.w += fmaxf(u2.w * sa.w + ha.w, 0.f);
                    a3.x += fmaxf(u3.x * sa.x + ha.x, 0.f); a3.y += fmaxf(u3.y * sa.y + ha.y, 0.f);
                    a3.z += fmaxf(u3.z * sa.z + ha.z, 0.f); a3.w += fmaxf(u3.w * sa.w + ha.w, 0.f);
                }
                a0.x = fmaxf(a0.x, 0.f); a0.y = fmaxf(a0.y, 0.f); a0.z = fmaxf(a0.z, 0.f); a0.w = fmaxf(a0.w, 0.f);
                a1.x = fmaxf(a1.x, 0.f); a1.y = fmaxf(a1.y, 0.f); a1.z = fmaxf(a1.z, 0.f); a1.w = fmaxf(a1.w, 0.f);
                a2.x = fmaxf(a2.x, 0.f); a2.y = fmaxf(a2.y, 0.f); a2.z = fmaxf(a2.z, 0.f); a2.w = fmaxf(a2.w, 0.f);
                a3.x = fmaxf(a3.x, 0.f); a3.y = fmaxf(a3.y, 0.f); a3.z = fmaxf(a3.z, 0.f); a3.w = fmaxf(a3.w, 0.f);
            }
            int k = kg * 4;
            float w0 = Wl[(k + 0) * 64 + lane];
            float w1 = Wl[(k + 1) * 64 + lane];
            float w2 = Wl[(k + 2) * 64 + lane];
            float w3 = Wl[(k + 3) * 64 + lane];
            acc0 = fmaf(a0.w, w3, fmaf(a0.z, w2, fmaf(a0.y, w1, fmaf(a0.x, w0, acc0))));
            acc1 = fmaf(a1.w, w3, fmaf(a1.z, w2, fmaf(a1.y, w1, fmaf(a1.x, w0, acc1))));
            acc2 = fmaf(a2.w, w3, fmaf(a2.z, w2, fmaf(a2.y, w1, fmaf(a2.x, w0, acc2))));
            acc3 = fmaf(a3.w, w3, fmaf(a3.z, w2, fmaf(a3.y, w1, fmaf(a3.x, w0, acc3))));
        }
        out[(size_t)base * 64 + lane] = acc0 * dis[base];
        if (base + 1 < N) out[(size_t)(base + 1) * 64 + lane] = acc1 * dis[r1];
        if (base + 2 < N) out[(size_t)(base + 2) * 64 + lane] = acc2 * dis[r2];
        if (base + 3 < N) out[(size_t)(base + 3) * 64 + lane] = acc3 * dis[r3];
    }
}

// ---------- quad-gather: one wave per dst row, 4 src rows per iteration ----------
// z[n] = dis[n] * (sum_{s in in(n)} hs[s] + hs[n]) + b ;  accumulate BN stats.
__global__ void __launch_bounds__(256) k_gather4(const int* __restrict__ row_ptr,
                                                 const int* __restrict__ cnt,
                                                 const int* __restrict__ csr_src,
                                                 const float* __restrict__ dis,
                                                 const float* __restrict__ hs,
                                                 const float* __restrict__ b,
                                                 float* __restrict__ z,
                                                 float* __restrict__ stats, int N) {
    int tid  = threadIdx.x;
    int lane = tid & 63;
    int w    = tid >> 6;       // wave 0..3
    int grp  = lane >> 4;      // which src row of the quad
    int sub  = lane & 15;      // float4 slot within row
    float4 psum = {0.f, 0.f, 0.f, 0.f}, psq = {0.f, 0.f, 0.f, 0.f};
    for (int n = blockIdx.x * 4 + w; n < N; n += gridDim.x * 4) {
        int start = row_ptr[n];
        int c     = cnt[n];
        float4 acc = {0.f, 0.f, 0.f, 0.f};
        int j = 0;
#pragma unroll 2
        for (; j + 4 <= c; j += 4) {
            int s = csr_src[start + j + grp];
            float4 v = *(const float4*)(hs + (size_t)s * 64 + sub * 4);
            acc.x += v.x; acc.y += v.y; acc.z += v.z; acc.w += v.w;
        }
        if (j + grp < c) {
            int s = csr_src[start + j + grp];
            float4 v = *(const float4*)(hs + (size_t)s * 64 + sub * 4);
            acc.x += v.x; acc.y += v.y; acc.z += v.z; acc.w += v.w;
        }
        // reduce the 4 groups: lanes L, L^16, L^32, L^48
        acc.x += __shfl_xor(acc.x, 16); acc.y += __shfl_xor(acc.y, 16);
        acc.z += __shfl_xor(acc.z, 16); acc.w += __shfl_xor(acc.w, 16);
        acc.x += __shfl_xor(acc.x, 32); acc.y += __shfl_xor(acc.y, 32);
        acc.z += __shfl_xor(acc.z, 32); acc.w += __shfl_xor(acc.w, 32);
        if (grp == 0) {
            float4 self = *(const float4*)(hs + (size_t)n * 64 + sub * 4);
            float4 vb   = *(const float4*)(b + sub * 4);
            float  d    = dis[n];
            float4 v;
            v.x = (acc.x + self.x) * d + vb.x;
            v.y = (acc.y + self.y) * d + vb.y;
            v.z = (acc.z + self.z) * d + vb.z;
            v.w = (acc.w + self.w) * d + vb.w;
            *(float4*)(z + (size_t)n * 64 + sub * 4) = v;
            psum.x += v.x; psum.y += v.y; psum.z += v.z; psum.w += v.w;
            psq.x += v.x * v.x; psq.y += v.y * v.y; psq.z += v.z * v.z; psq.w += v.w * v.w;
        }
    }
    __shared__ float ssum[4][64], ssq[4][64];
    if (grp == 0) {
        *(float4*)&ssum[w][sub * 4] = psum;
        *(float4*)&ssq[w][sub * 4]  = psq;
    }
    __syncthreads();
    if (tid < 64) {
        float s = ssum[0][tid] + ssum[1][tid] + ssum[2][tid] + ssum[3][tid];
        float q = ssq[0][tid] + ssq[1][tid] + ssq[2][tid] + ssq[3][tid];
        atomicAdd(&stats[tid], s);
        atomicAdd(&stats[64 + tid], q);
    }
}

// ---------- layer-3 normalize + relu + segmented pool (batch sorted) ----------
__global__ void k_norm_pool(const float* __restrict__ z, const float* __restrict__ stats,
                            const float* __restrict__ g, const float* __restrict__ be,
                            const int* __restrict__ batch, float* __restrict__ psums,
                            float* __restrict__ pcnt, float invN, int N, int per) {
    int lane = threadIdx.x & 63;
    int wave = (blockIdx.x * blockDim.x + threadIdx.x) >> 6;
    int begin = wave * per;
    if (begin >= N) return;
    int end = begin + per; if (end > N) end = N;
    float mu  = stats[lane] * invN;
    float var = stats[64 + lane] * invN - mu * mu;
    float sc  = g[lane] * rsqrtf(var + 1e-5f);
    float sh  = be[lane] - mu * sc;
    int   cur = batch[begin];
    float run = 0.f;
    int   crun = 0;
    for (int n = begin; n < end; ++n) {
        int gg = batch[n];
        if (gg != cur) {
            atomicAdd(&psums[(size_t)cur * 64 + lane], run);
            if (lane == 0) atomicAdd(&pcnt[cur], (float)crun);
            run = 0.f; crun = 0; cur = gg;
        }
        float v = fmaxf(z[(size_t)n * 64 + lane] * sc + sh, 0.f);
        run += v; crun++;
    }
    atomicAdd(&psums[(size_t)cur * 64 + lane], run);
    if (lane == 0) atomicAdd(&pcnt[cur], (float)crun);
}

// ---------- FF branch + fusion head ----------
__global__ void k_head(const float* __restrict__ sigma, const float* __restrict__ Wf1,
                       const float* __restrict__ bf1, const float* __restrict__ Wf2,
                       const float* __restrict__ bf2, const float* __restrict__ Wfu,
                       const float* __restrict__ bfu, const float* __restrict__ sums,
                       const float* __restrict__ cnt, float* __restrict__ out) {
    int g = blockIdx.x;
    int t = threadIdx.x;  // 128 threads
    __shared__ float srow[64], f1[128], f2[64];
    if (t < 64) srow[t] = sigma[(size_t)g * 64 + t];
    __syncthreads();
    {
        float acc = bf1[t];
        for (int s = 0; s < 64; ++s) acc += srow[s] * Wf1[s * 128 + t];
        f1[t] = fmaxf(acc, 0.f);
    }
    __syncthreads();
    if (t < 64) {
        float a2 = bf2[t];
        for (int k = 0; k < 128; ++k) a2 += f1[k] * Wf2[k * 64 + t];
        f2[t] = fmaxf(a2, 0.f);
    }
    __syncthreads();
    if (t < 64) {
        float inv    = 1.0f / fmaxf(cnt[g], 1.0f);
        float pooled = sums[(size_t)g * 64 + t] * inv;
        float contrib = pooled * Wfu[t] + f2[t] * Wfu[64 + t];
#pragma unroll
        for (int o = 32; o > 0; o >>= 1) contrib += __shfl_down(contrib, o);
        if (t == 0) out[g] = contrib + bfu[0];
    }
}

extern "C" void kernel_launch(void* const* d_in, const int* in_sizes, int n_in,
                              void* d_out, int out_size, void* d_ws, size_t ws_size,
                              hipStream_t stream) {
    const float* x     = (const float*)d_in[0];
    const int*   ei    = (const int*)d_in[1];
    const int*   batch = (const int*)d_in[2];
    const float* sigma = (const float*)d_in[3];
    const float* W1 = (const float*)d_in[4];  const float* b1 = (const float*)d_in[5];
    const float* g1 = (const float*)d_in[6];  const float* be1 = (const float*)d_in[7];
    const float* W2 = (const float*)d_in[8];  const float* b2 = (const float*)d_in[9];
    const float* g2 = (const float*)d_in[10]; const float* be2 = (const float*)d_in[11];
    const float* W3 = (const float*)d_in[12]; const float* b3 = (const float*)d_in[13];
    const float* g3 = (const float*)d_in[14]; const float* be3 = (const float*)d_in[15];
    const float* Wf1 = (const float*)d_in[16]; const float* bf1 = (const float*)d_in[17];
    const float* Wf2 = (const float*)d_in[18]; const float* bf2 = (const float*)d_in[19];
    const float* Wfu = (const float*)d_in[20]; const float* bfu = (const float*)d_in[21];

    const int N = in_sizes[0] / 128;
    const int E = in_sizes[1] / 2;
    const int G = in_sizes[3] / 64;
    const int* src = ei;
    const int* dst = ei + E;

    float* ws   = (float*)d_ws;
    float* bufA = ws;                       // hs (pre-scaled gemm out)
    float* bufB = bufA + (size_t)N * 64;    // z1 / z3
    float* bufC = bufB + (size_t)N * 64;    // z2
    float* dis  = bufC + (size_t)N * 64;
    int*   row_ptr = (int*)(dis + N);
    int*   bsum    = row_ptr + N;
    int*   csr_src = bsum + 1024;
    // ---- contiguous zero region ----
    int*   cnt     = csr_src + E;
    int*   cursor  = cnt + N;
    float* stats1  = (float*)(cursor + N);
    float* stats2  = stats1 + 128;
    float* stats3  = stats2 + 128;
    float* psums   = stats3 + 128;
    float* pcnt    = psums + (size_t)G * 64;
    size_t zero_bytes = ((char*)(pcnt + G)) - ((char*)cnt);

    const float invN = 1.0f / (float)N;
    const int nb     = (N + 255) / 256;

    hipMemsetAsync(cnt, 0, zero_bytes, stream);

    // ---- CSR build + degrees ----
    k_hist<<<(E + 255) / 256, 256, 0, stream>>>(dst, cnt, E);
    k_scanA<<<nb, 256, 0, stream>>>(cnt, bsum, N);
    k_scanB<<<1, 1024, 0, stream>>>(bsum, nb);
    k_scanC<<<nb, 256, 0, stream>>>(cnt, bsum, row_ptr, dis, N);
    k_fill<<<(E + 255) / 256, 256, 0, stream>>>(src, dst, row_ptr, cursor, csr_src, E);

    // ---- layer 1: gemm(x) -> hs1, gather -> z1 (bufB) ----
    k_gemm_f<128, 0><<<1024, 256, 0, stream>>>(x, nullptr, W1, dis,
        nullptr, nullptr, nullptr, nullptr, nullptr, nullptr, bufA, invN, N);
    k_gather4<<<2048, 256, 0, stream>>>(row_ptr, cnt, csr_src, dis, bufA, b1, bufB, stats1, N);

    // ---- layer 2: gemm(relu(bn1(z1))) -> hs2, gather -> z2 (bufC) ----
    k_gemm_f<64, 1><<<1024, 256, 0, stream>>>(bufB, nullptr, W2, dis,
        stats1, g1, be1, nullptr, nullptr, nullptr, bufA, invN, N);
    k_gather4<<<2048, 256, 0, stream>>>(row_ptr, cnt, csr_src, dis, bufA, b2, bufC, stats2, N);

    // ---- layer 3: gemm(relu(bn2(z2)+relu(bn1(z1)))) -> hs3, gather -> z3 (bufB) ----
    k_gemm_f<64, 2><<<1024, 256, 0, stream>>>(bufC, bufB, W3, dis,
        stats2, g2, be2, stats1, g1, be1, bufA, invN, N);
    k_gather4<<<2048, 256, 0, stream>>>(row_ptr, cnt, csr_src, dis, bufA, b3, bufB, stats3, N);

    // ---- fused normalize + relu + pool ----
    {
        const int waves = 8192;
        int per = (N + waves - 1) / waves;
        k_norm_pool<<<2048, 256, 0, stream>>>(bufB, stats3, g3, be3, batch, psums, pcnt, invN, N, per);
    }

    // ---- head ----
    k_head<<<G, 128, 0, stream>>>(sigma, Wf1, bf1, Wf2, bf2, Wfu, bfu, psums, pcnt, (float*)d_out);
}

// Round 6
// 479.671 us; speedup vs baseline: 1.0971x; 1.0971x over previous
//
#include <hip/hip_runtime.h>
#include <hip/hip_bf16.h>

// ---------- CSR build ----------
__global__ void k_hist(const int* __restrict__ dst, int* __restrict__ cnt, int E) {
    int e = blockIdx.x * blockDim.x + threadIdx.x;
    if (e < E) atomicAdd(&cnt[dst[e]], 1);
}

__global__ void k_scanA(const int* __restrict__ cnt, int* __restrict__ bsum, int N) {
    __shared__ int sh[256];
    int i = blockIdx.x * 256 + threadIdx.x;
    sh[threadIdx.x] = (i < N) ? cnt[i] : 0;
    __syncthreads();
    for (int off = 128; off > 0; off >>= 1) {
        if (threadIdx.x < off) sh[threadIdx.x] += sh[threadIdx.x + off];
        __syncthreads();
    }
    if (threadIdx.x == 0) bsum[blockIdx.x] = sh[0];
}

__global__ void k_scanB(int* __restrict__ bsum, int nb) {
    __shared__ int sh[1024];
    int t = threadIdx.x;
    sh[t] = (t < nb) ? bsum[t] : 0;
    __syncthreads();
    for (int off = 1; off < 1024; off <<= 1) {
        int v = (t >= off) ? sh[t - off] : 0;
        __syncthreads();
        sh[t] += v;
        __syncthreads();
    }
    if (t < nb) bsum[t] = (t == 0) ? 0 : sh[t - 1];
}

__global__ void k_scanC(const int* __restrict__ cnt, const int* __restrict__ boff,
                        int* __restrict__ row_ptr, float* __restrict__ dis, int N) {
    __shared__ int sh[256];
    int i = blockIdx.x * 256 + threadIdx.x;
    int v = (i < N) ? cnt[i] : 0;
    sh[threadIdx.x] = v;
    __syncthreads();
    for (int off = 1; off < 256; off <<= 1) {
        int u = (threadIdx.x >= off) ? sh[threadIdx.x - off] : 0;
        __syncthreads();
        sh[threadIdx.x] += u;
        __syncthreads();
    }
    if (i < N) {
        row_ptr[i] = sh[threadIdx.x] - v + boff[blockIdx.x];
        dis[i] = rsqrtf((float)v + 1.0f);
    }
}

__global__ void k_fill(const int* __restrict__ src, const int* __restrict__ dst,
                       const int* __restrict__ row_ptr, int* __restrict__ cursor,
                       int* __restrict__ csr_src, int E) {
    int e = blockIdx.x * blockDim.x + threadIdx.x;
    if (e < E) {
        int d = dst[e];
        int pos = row_ptr[d] + atomicAdd(&cursor[d], 1);
        csr_src[pos] = src[e];
    }
}

// ---------- row-looped GEMM: out[N][64] = (in[N][K] @ W[K][64]) * dis[row] ----------
// Lean: 32 VGPR, W staged once per block, 4 rows per wave-iteration.
template <int K>
__global__ void __launch_bounds__(256) k_gemm_big(const float* __restrict__ in,
                                                  const float* __restrict__ W,
                                                  const float* __restrict__ dis,
                                                  float* __restrict__ out, int N) {
    __shared__ float Wl[K * 64];
    for (int i = threadIdx.x; i < K * 16; i += 256)
        ((float4*)Wl)[i] = ((const float4*)W)[i];
    __syncthreads();
    int lane = threadIdx.x & 63;
    int wid  = blockIdx.x * 4 + (threadIdx.x >> 6);
    int nw   = gridDim.x * 4;
    int ngrp = (N + 3) >> 2;
    for (int g = wid; g < ngrp; g += nw) {
        int base = g * 4;
        int r1 = min(base + 1, N - 1), r2 = min(base + 2, N - 1), r3 = min(base + 3, N - 1);
        const float4* p0 = (const float4*)(in + (size_t)base * K);
        const float4* p1 = (const float4*)(in + (size_t)r1 * K);
        const float4* p2 = (const float4*)(in + (size_t)r2 * K);
        const float4* p3 = (const float4*)(in + (size_t)r3 * K);
        float acc0 = 0.f, acc1 = 0.f, acc2 = 0.f, acc3 = 0.f;
#pragma unroll 4
        for (int kg = 0; kg < K / 4; ++kg) {
            float4 a0 = p0[kg], a1 = p1[kg], a2 = p2[kg], a3 = p3[kg];
            int k = kg * 4;
            float w0 = Wl[(k + 0) * 64 + lane];
            float w1 = Wl[(k + 1) * 64 + lane];
            float w2 = Wl[(k + 2) * 64 + lane];
            float w3 = Wl[(k + 3) * 64 + lane];
            acc0 = fmaf(a0.w, w3, fmaf(a0.z, w2, fmaf(a0.y, w1, fmaf(a0.x, w0, acc0))));
            acc1 = fmaf(a1.w, w3, fmaf(a1.z, w2, fmaf(a1.y, w1, fmaf(a1.x, w0, acc1))));
            acc2 = fmaf(a2.w, w3, fmaf(a2.z, w2, fmaf(a2.y, w1, fmaf(a2.x, w0, acc2))));
            acc3 = fmaf(a3.w, w3, fmaf(a3.z, w2, fmaf(a3.y, w1, fmaf(a3.x, w0, acc3))));
        }
        out[(size_t)base * 64 + lane] = acc0 * dis[base];
        if (base + 1 < N) out[(size_t)(base + 1) * 64 + lane] = acc1 * dis[r1];
        if (base + 2 < N) out[(size_t)(base + 2) * 64 + lane] = acc2 * dis[r2];
        if (base + 3 < N) out[(size_t)(base + 3) * 64 + lane] = acc3 * dis[r3];
    }
}

// ---------- quad-gather: one wave per dst row, 4 src rows per iteration ----------
__global__ void __launch_bounds__(256) k_gather4(const int* __restrict__ row_ptr,
                                                 const int* __restrict__ cnt,
                                                 const int* __restrict__ csr_src,
                                                 const float* __restrict__ dis,
                                                 const float* __restrict__ hs,
                                                 const float* __restrict__ b,
                                                 float* __restrict__ z,
                                                 float* __restrict__ stats, int N) {
    int tid  = threadIdx.x;
    int lane = tid & 63;
    int w    = tid >> 6;       // wave 0..3
    int grp  = lane >> 4;      // which src row of the quad
    int sub  = lane & 15;      // float4 slot within row
    float4 psum = {0.f, 0.f, 0.f, 0.f}, psq = {0.f, 0.f, 0.f, 0.f};
    for (int n = blockIdx.x * 4 + w; n < N; n += gridDim.x * 4) {
        int start = row_ptr[n];
        int c     = cnt[n];
        float4 acc = {0.f, 0.f, 0.f, 0.f};
        int j = 0;
#pragma unroll 2
        for (; j + 4 <= c; j += 4) {
            int s = csr_src[start + j + grp];
            float4 v = *(const float4*)(hs + (size_t)s * 64 + sub * 4);
            acc.x += v.x; acc.y += v.y; acc.z += v.z; acc.w += v.w;
        }
        if (j + grp < c) {
            int s = csr_src[start + j + grp];
            float4 v = *(const float4*)(hs + (size_t)s * 64 + sub * 4);
            acc.x += v.x; acc.y += v.y; acc.z += v.z; acc.w += v.w;
        }
        acc.x += __shfl_xor(acc.x, 16); acc.y += __shfl_xor(acc.y, 16);
        acc.z += __shfl_xor(acc.z, 16); acc.w += __shfl_xor(acc.w, 16);
        acc.x += __shfl_xor(acc.x, 32); acc.y += __shfl_xor(acc.y, 32);
        acc.z += __shfl_xor(acc.z, 32); acc.w += __shfl_xor(acc.w, 32);
        if (grp == 0) {
            float4 self = *(const float4*)(hs + (size_t)n * 64 + sub * 4);
            float4 vb   = *(const float4*)(b + sub * 4);
            float  d    = dis[n];
            float4 v;
            v.x = (acc.x + self.x) * d + vb.x;
            v.y = (acc.y + self.y) * d + vb.y;
            v.z = (acc.z + self.z) * d + vb.z;
            v.w = (acc.w + self.w) * d + vb.w;
            *(float4*)(z + (size_t)n * 64 + sub * 4) = v;
            psum.x += v.x; psum.y += v.y; psum.z += v.z; psum.w += v.w;
            psq.x += v.x * v.x; psq.y += v.y * v.y; psq.z += v.z * v.z; psq.w += v.w * v.w;
        }
    }
    __shared__ float ssum[4][64], ssq[4][64];
    if (grp == 0) {
        *(float4*)&ssum[w][sub * 4] = psum;
        *(float4*)&ssq[w][sub * 4]  = psq;
    }
    __syncthreads();
    if (tid < 64) {
        float s = ssum[0][tid] + ssum[1][tid] + ssum[2][tid] + ssum[3][tid];
        float q = ssq[0][tid] + ssq[1][tid] + ssq[2][tid] + ssq[3][tid];
        atomicAdd(&stats[tid], s);
        atomicAdd(&stats[64 + tid], q);
    }
}

// ---------- normalize (inline BN finalize) + (residual) + relu ----------
__global__ void k_norm(const float* __restrict__ z, const float* __restrict__ stats,
                       const float* __restrict__ g, const float* __restrict__ be,
                       const float* __restrict__ res, float* __restrict__ out,
                       float invN, int total) {
    int i = blockIdx.x * blockDim.x + threadIdx.x;
    if (i >= total) return;
    int c = i & 63;
    float mu  = stats[c] * invN;
    float var = stats[64 + c] * invN - mu * mu;
    float sc  = g[c] * rsqrtf(var + 1e-5f);
    float sh  = be[c] - mu * sc;
    float v = z[i] * sc + sh;
    if (res) v += res[i];
    out[i] = fmaxf(v, 0.f);
}

// ---------- layer-3 normalize + relu + segmented pool (batch sorted) ----------
__global__ void k_norm_pool(const float* __restrict__ z, const float* __restrict__ stats,
                            const float* __restrict__ g, const float* __restrict__ be,
                            const int* __restrict__ batch, float* __restrict__ psums,
                            float* __restrict__ pcnt, float invN, int N, int per) {
    int lane = threadIdx.x & 63;
    int wave = (blockIdx.x * blockDim.x + threadIdx.x) >> 6;
    int begin = wave * per;
    if (begin >= N) return;
    int end = begin + per; if (end > N) end = N;
    float mu  = stats[lane] * invN;
    float var = stats[64 + lane] * invN - mu * mu;
    float sc  = g[lane] * rsqrtf(var + 1e-5f);
    float sh  = be[lane] - mu * sc;
    int   cur = batch[begin];
    float run = 0.f;
    int   crun = 0;
    for (int n = begin; n < end; ++n) {
        int gg = batch[n];
        if (gg != cur) {
            atomicAdd(&psums[(size_t)cur * 64 + lane], run);
            if (lane == 0) atomicAdd(&pcnt[cur], (float)crun);
            run = 0.f; crun = 0; cur = gg;
        }
        float v = fmaxf(z[(size_t)n * 64 + lane] * sc + sh, 0.f);
        run += v; crun++;
    }
    atomicAdd(&psums[(size_t)cur * 64 + lane], run);
    if (lane == 0) atomicAdd(&pcnt[cur], (float)crun);
}

// ---------- FF branch + fusion head ----------
__global__ void k_head(const float* __restrict__ sigma, const float* __restrict__ Wf1,
                       const float* __restrict__ bf1, const float* __restrict__ Wf2,
                       const float* __restrict__ bf2, const float* __restrict__ Wfu,
                       const float* __restrict__ bfu, const float* __restrict__ sums,
                       const float* __restrict__ cnt, float* __restrict__ out) {
    int g = blockIdx.x;
    int t = threadIdx.x;  // 128 threads
    __shared__ float srow[64], f1[128], f2[64];
    if (t < 64) srow[t] = sigma[(size_t)g * 64 + t];
    __syncthreads();
    {
        float acc = bf1[t];
        for (int s = 0; s < 64; ++s) acc += srow[s] * Wf1[s * 128 + t];
        f1[t] = fmaxf(acc, 0.f);
    }
    __syncthreads();
    if (t < 64) {
        float a2 = bf2[t];
        for (int k = 0; k < 128; ++k) a2 += f1[k] * Wf2[k * 64 + t];
        f2[t] = fmaxf(a2, 0.f);
    }
    __syncthreads();
    if (t < 64) {
        float inv    = 1.0f / fmaxf(cnt[g], 1.0f);
        float pooled = sums[(size_t)g * 64 + t] * inv;
        float contrib = pooled * Wfu[t] + f2[t] * Wfu[64 + t];
#pragma unroll
        for (int o = 32; o > 0; o >>= 1) contrib += __shfl_down(contrib, o);
        if (t == 0) out[g] = contrib + bfu[0];
    }
}

extern "C" void kernel_launch(void* const* d_in, const int* in_sizes, int n_in,
                              void* d_out, int out_size, void* d_ws, size_t ws_size,
                              hipStream_t stream) {
    const float* x     = (const float*)d_in[0];
    const int*   ei    = (const int*)d_in[1];
    const int*   batch = (const int*)d_in[2];
    const float* sigma = (const float*)d_in[3];
    const float* W1 = (const float*)d_in[4];  const float* b1 = (const float*)d_in[5];
    const float* g1 = (const float*)d_in[6];  const float* be1 = (const float*)d_in[7];
    const float* W2 = (const float*)d_in[8];  const float* b2 = (const float*)d_in[9];
    const float* g2 = (const float*)d_in[10]; const float* be2 = (const float*)d_in[11];
    const float* W3 = (const float*)d_in[12]; const float* b3 = (const float*)d_in[13];
    const float* g3 = (const float*)d_in[14]; const float* be3 = (const float*)d_in[15];
    const float* Wf1 = (const float*)d_in[16]; const float* bf1 = (const float*)d_in[17];
    const float* Wf2 = (const float*)d_in[18]; const float* bf2 = (const float*)d_in[19];
    const float* Wfu = (const float*)d_in[20]; const float* bfu = (const float*)d_in[21];

    const int N = in_sizes[0] / 128;
    const int E = in_sizes[1] / 2;
    const int G = in_sizes[3] / 64;
    const int* src = ei;
    const int* dst = ei + E;

    float* ws   = (float*)d_ws;
    float* bufA = ws;                       // hs (pre-scaled gemm out)
    float* bufB = bufA + (size_t)N * 64;    // z
    float* bufC = bufB + (size_t)N * 64;    // h (activations)
    float* dis  = bufC + (size_t)N * 64;
    int*   row_ptr = (int*)(dis + N);
    int*   bsum    = row_ptr + N;
    int*   csr_src = bsum + 1024;
    // ---- contiguous zero region ----
    int*   cnt     = csr_src + E;
    int*   cursor  = cnt + N;
    float* stats1  = (float*)(cursor + N);
    float* stats2  = stats1 + 128;
    float* stats3  = stats2 + 128;
    float* psums   = stats3 + 128;
    float* pcnt    = psums + (size_t)G * 64;
    size_t zero_bytes = ((char*)(pcnt + G)) - ((char*)cnt);

    const float invN = 1.0f / (float)N;
    const int totNH  = N * 64;
    const int nb     = (N + 255) / 256;

    hipMemsetAsync(cnt, 0, zero_bytes, stream);

    // ---- CSR build + degrees ----
    k_hist<<<(E + 255) / 256, 256, 0, stream>>>(dst, cnt, E);
    k_scanA<<<nb, 256, 0, stream>>>(cnt, bsum, N);
    k_scanB<<<1, 1024, 0, stream>>>(bsum, nb);
    k_scanC<<<nb, 256, 0, stream>>>(cnt, bsum, row_ptr, dis, N);
    k_fill<<<(E + 255) / 256, 256, 0, stream>>>(src, dst, row_ptr, cursor, csr_src, E);

    // ---- layer 1 ----
    k_gemm_big<128><<<1024, 256, 0, stream>>>(x, W1, dis, bufA, N);
    k_gather4<<<2048, 256, 0, stream>>>(row_ptr, cnt, csr_src, dis, bufA, b1, bufB, stats1, N);
    k_norm<<<(totNH + 255) / 256, 256, 0, stream>>>(bufB, stats1, g1, be1, nullptr, bufC, invN, totNH);

    // ---- layer 2 (residual = bufC = h1) ----
    k_gemm_big<64><<<1024, 256, 0, stream>>>(bufC, W2, dis, bufA, N);
    k_gather4<<<2048, 256, 0, stream>>>(row_ptr, cnt, csr_src, dis, bufA, b2, bufB, stats2, N);
    k_norm<<<(totNH + 255) / 256, 256, 0, stream>>>(bufB, stats2, g2, be2, bufC, bufA, invN, totNH); // h2 -> bufA

    // ---- layer 3 ----
    k_gemm_big<64><<<1024, 256, 0, stream>>>(bufA, W3, dis, bufC, N);               // hs3 -> bufC
    k_gather4<<<2048, 256, 0, stream>>>(row_ptr, cnt, csr_src, dis, bufC, b3, bufB, stats3, N);

    // ---- fused normalize + relu + pool ----
    {
        const int waves = 8192;
        int per = (N + waves - 1) / waves;
        k_norm_pool<<<2048, 256, 0, stream>>>(bufB, stats3, g3, be3, batch, psums, pcnt, invN, N, per);
    }

    // ---- head ----
    k_head<<<G, 128, 0, stream>>>(sigma, Wf1, bf1, Wf2, bf2, Wfu, bfu, psums, pcnt, (float*)d_out);
}

// Round 7
// 456.195 us; speedup vs baseline: 1.1535x; 1.0515x over previous
//
#include <hip/hip_runtime.h>
#include <hip/hip_bf16.h>

__device__ __forceinline__ float b2f(unsigned short u) {
    union { unsigned int i; float f; } t; t.i = ((unsigned int)u) << 16; return t.f;
}

// ---------- CSR build ----------
__global__ void k_hist(const int* __restrict__ dst, int* __restrict__ cnt, int E) {
    int e = blockIdx.x * blockDim.x + threadIdx.x;
    if (e < E) atomicAdd(&cnt[dst[e]], 1);
}

__global__ void k_scanA(const int* __restrict__ cnt, int* __restrict__ bsum, int N) {
    __shared__ int sh[256];
    int i = blockIdx.x * 256 + threadIdx.x;
    sh[threadIdx.x] = (i < N) ? cnt[i] : 0;
    __syncthreads();
    for (int off = 128; off > 0; off >>= 1) {
        if (threadIdx.x < off) sh[threadIdx.x] += sh[threadIdx.x + off];
        __syncthreads();
    }
    if (threadIdx.x == 0) bsum[blockIdx.x] = sh[0];
}

__global__ void k_scanB(int* __restrict__ bsum, int nb) {
    __shared__ int sh[1024];
    int t = threadIdx.x;
    sh[t] = (t < nb) ? bsum[t] : 0;
    __syncthreads();
    for (int off = 1; off < 1024; off <<= 1) {
        int v = (t >= off) ? sh[t - off] : 0;
        __syncthreads();
        sh[t] += v;
        __syncthreads();
    }
    if (t < nb) bsum[t] = (t == 0) ? 0 : sh[t - 1];
}

// local scan + write row_ptr, packed (start,cnt), and dis
__global__ void k_scanC(const int* __restrict__ cnt, const int* __restrict__ boff,
                        int* __restrict__ row_ptr, int2* __restrict__ rc,
                        float* __restrict__ dis, int N) {
    __shared__ int sh[256];
    int i = blockIdx.x * 256 + threadIdx.x;
    int v = (i < N) ? cnt[i] : 0;
    sh[threadIdx.x] = v;
    __syncthreads();
    for (int off = 1; off < 256; off <<= 1) {
        int u = (threadIdx.x >= off) ? sh[threadIdx.x - off] : 0;
        __syncthreads();
        sh[threadIdx.x] += u;
        __syncthreads();
    }
    if (i < N) {
        int start = sh[threadIdx.x] - v + boff[blockIdx.x];
        row_ptr[i] = start;
        rc[i] = make_int2(start, v);
        dis[i] = rsqrtf((float)v + 1.0f);
    }
}

__global__ void k_fill(const int* __restrict__ src, const int* __restrict__ dst,
                       const int* __restrict__ row_ptr, int* __restrict__ cursor,
                       int* __restrict__ csr_src, int E) {
    int e = blockIdx.x * blockDim.x + threadIdx.x;
    if (e < E) {
        int d = dst[e];
        int pos = row_ptr[d] + atomicAdd(&cursor[d], 1);
        csr_src[pos] = src[e];
    }
}

// ---------- row-looped GEMM: out_bf16[N][64] = (in[N][K] @ W[K][64]) * dis[row] ----------
template <int K>
__global__ void __launch_bounds__(256) k_gemm_big(const float* __restrict__ in,
                                                  const float* __restrict__ W,
                                                  const float* __restrict__ dis,
                                                  __hip_bfloat16* __restrict__ out, int N) {
    __shared__ float Wl[K * 64];
    for (int i = threadIdx.x; i < K * 16; i += 256)
        ((float4*)Wl)[i] = ((const float4*)W)[i];
    __syncthreads();
    int lane = threadIdx.x & 63;
    int wid  = blockIdx.x * 4 + (threadIdx.x >> 6);
    int nw   = gridDim.x * 4;
    int ngrp = (N + 3) >> 2;
    for (int g = wid; g < ngrp; g += nw) {
        int base = g * 4;
        int r1 = min(base + 1, N - 1), r2 = min(base + 2, N - 1), r3 = min(base + 3, N - 1);
        const float4* p0 = (const float4*)(in + (size_t)base * K);
        const float4* p1 = (const float4*)(in + (size_t)r1 * K);
        const float4* p2 = (const float4*)(in + (size_t)r2 * K);
        const float4* p3 = (const float4*)(in + (size_t)r3 * K);
        float acc0 = 0.f, acc1 = 0.f, acc2 = 0.f, acc3 = 0.f;
#pragma unroll 4
        for (int kg = 0; kg < K / 4; ++kg) {
            float4 a0 = p0[kg], a1 = p1[kg], a2 = p2[kg], a3 = p3[kg];
            int k = kg * 4;
            float w0 = Wl[(k + 0) * 64 + lane];
            float w1 = Wl[(k + 1) * 64 + lane];
            float w2 = Wl[(k + 2) * 64 + lane];
            float w3 = Wl[(k + 3) * 64 + lane];
            acc0 = fmaf(a0.w, w3, fmaf(a0.z, w2, fmaf(a0.y, w1, fmaf(a0.x, w0, acc0))));
            acc1 = fmaf(a1.w, w3, fmaf(a1.z, w2, fmaf(a1.y, w1, fmaf(a1.x, w0, acc1))));
            acc2 = fmaf(a2.w, w3, fmaf(a2.z, w2, fmaf(a2.y, w1, fmaf(a2.x, w0, acc2))));
            acc3 = fmaf(a3.w, w3, fmaf(a3.z, w2, fmaf(a3.y, w1, fmaf(a3.x, w0, acc3))));
        }
        out[(size_t)base * 64 + lane] = __float2bfloat16(acc0 * dis[base]);
        if (base + 1 < N) out[(size_t)(base + 1) * 64 + lane] = __float2bfloat16(acc1 * dis[r1]);
        if (base + 2 < N) out[(size_t)(base + 2) * 64 + lane] = __float2bfloat16(acc2 * dis[r2]);
        if (base + 3 < N) out[(size_t)(base + 3) * 64 + lane] = __float2bfloat16(acc3 * dis[r3]);
    }
}

// ---------- oct-gather: one wave per dst row, 8 bf16 src rows per memory instruction ----------
// z[n] = dis[n] * (sum_{s in in(n)} hs[s] + hs[n]) + b ;  accumulate BN stats (f32).
__global__ void __launch_bounds__(256) k_gather8(const int2* __restrict__ rc,
                                                 const int* __restrict__ csr_src,
                                                 const float* __restrict__ dis,
                                                 const __hip_bfloat16* __restrict__ hs,
                                                 const float* __restrict__ b,
                                                 float* __restrict__ z,
                                                 float* __restrict__ stats, int N) {
    const unsigned short* hsu = (const unsigned short*)hs;
    int tid  = threadIdx.x;
    int lane = tid & 63;
    int w    = tid >> 6;       // wave 0..3
    int grp  = lane >> 3;      // which of 8 src rows
    int sub  = lane & 7;       // 16B segment (8 feats) within 128B row
    float vb[8];
    *(float4*)&vb[0] = *(const float4*)(b + sub * 8);
    *(float4*)&vb[4] = *(const float4*)(b + sub * 8 + 4);
    float ps[8] = {0,0,0,0,0,0,0,0}, pq[8] = {0,0,0,0,0,0,0,0};
    for (int n = blockIdx.x * 4 + w; n < N; n += gridDim.x * 4) {
        int2  rcv = rc[n];
        int   start = rcv.x, c = rcv.y;
        float d = dis[n];
        float4 selfraw = *(const float4*)(hsu + (size_t)n * 64 + sub * 8);
        float acc[8] = {0,0,0,0,0,0,0,0};
        int j = 0;
#pragma unroll 2
        for (; j + 8 <= c; j += 8) {
            int s = csr_src[start + j + grp];
            float4 raw = *(const float4*)(hsu + (size_t)s * 64 + sub * 8);
            const unsigned short* us = (const unsigned short*)&raw;
#pragma unroll
            for (int i = 0; i < 8; ++i) acc[i] += b2f(us[i]);
        }
        if (j + grp < c) {
            int s = csr_src[start + j + grp];
            float4 raw = *(const float4*)(hsu + (size_t)s * 64 + sub * 8);
            const unsigned short* us = (const unsigned short*)&raw;
#pragma unroll
            for (int i = 0; i < 8; ++i) acc[i] += b2f(us[i]);
        }
        // reduce over the 8 groups (lane bits 3,4,5)
#pragma unroll
        for (int i = 0; i < 8; ++i) acc[i] += __shfl_xor(acc[i], 8);
#pragma unroll
        for (int i = 0; i < 8; ++i) acc[i] += __shfl_xor(acc[i], 16);
#pragma unroll
        for (int i = 0; i < 8; ++i) acc[i] += __shfl_xor(acc[i], 32);
        if (grp == 0) {
            const unsigned short* su = (const unsigned short*)&selfraw;
            float v[8];
#pragma unroll
            for (int i = 0; i < 8; ++i) {
                v[i] = (acc[i] + b2f(su[i])) * d + vb[i];
                ps[i] += v[i];
                pq[i] += v[i] * v[i];
            }
            *(float4*)(z + (size_t)n * 64 + sub * 8)     = *(float4*)&v[0];
            *(float4*)(z + (size_t)n * 64 + sub * 8 + 4) = *(float4*)&v[4];
        }
    }
    __shared__ float ssum[4][64], ssq[4][64];
    if (grp == 0) {
        *(float4*)&ssum[w][sub * 8]     = *(float4*)&ps[0];
        *(float4*)&ssum[w][sub * 8 + 4] = *(float4*)&ps[4];
        *(float4*)&ssq[w][sub * 8]      = *(float4*)&pq[0];
        *(float4*)&ssq[w][sub * 8 + 4]  = *(float4*)&pq[4];
    }
    __syncthreads();
    if (tid < 64) {
        float s = ssum[0][tid] + ssum[1][tid] + ssum[2][tid] + ssum[3][tid];
        float q = ssq[0][tid] + ssq[1][tid] + ssq[2][tid] + ssq[3][tid];
        atomicAdd(&stats[tid], s);
        atomicAdd(&stats[64 + tid], q);
    }
}

// ---------- normalize (inline BN finalize) + (residual) + relu, float4 ----------
__global__ void k_norm4(const float* __restrict__ z, const float* __restrict__ stats,
                        const float* __restrict__ g, const float* __restrict__ be,
                        const float* __restrict__ res, float* __restrict__ out,
                        float invN, int total4) {
    int i = blockIdx.x * blockDim.x + threadIdx.x;
    if (i >= total4) return;
    int cb = (i & 15) * 4;
    float4 zv = ((const float4*)z)[i];
    float v[4] = {zv.x, zv.y, zv.z, zv.w};
#pragma unroll
    for (int k = 0; k < 4; ++k) {
        int c = cb + k;
        float mu  = stats[c] * invN;
        float var = stats[64 + c] * invN - mu * mu;
        float sc  = g[c] * rsqrtf(var + 1e-5f);
        float sh  = be[c] - mu * sc;
        v[k] = v[k] * sc + sh;
    }
    if (res) {
        float4 rv = ((const float4*)res)[i];
        v[0] += rv.x; v[1] += rv.y; v[2] += rv.z; v[3] += rv.w;
    }
    float4 o;
    o.x = fmaxf(v[0], 0.f); o.y = fmaxf(v[1], 0.f);
    o.z = fmaxf(v[2], 0.f); o.w = fmaxf(v[3], 0.f);
    ((float4*)out)[i] = o;
}

// ---------- layer-3 normalize + relu + segmented pool (batch sorted) ----------
__global__ void k_norm_pool(const float* __restrict__ z, const float* __restrict__ stats,
                            const float* __restrict__ g, const float* __restrict__ be,
                            const int* __restrict__ batch, float* __restrict__ psums,
                            float* __restrict__ pcnt, float invN, int N, int per) {
    int lane = threadIdx.x & 63;
    int wave = (blockIdx.x * blockDim.x + threadIdx.x) >> 6;
    int begin = wave * per;
    if (begin >= N) return;
    int end = begin + per; if (end > N) end = N;
    float mu  = stats[lane] * invN;
    float var = stats[64 + lane] * invN - mu * mu;
    float sc  = g[lane] * rsqrtf(var + 1e-5f);
    float sh  = be[lane] - mu * sc;
    int   cur = batch[begin];
    float run = 0.f;
    int   crun = 0;
    for (int n = begin; n < end; ++n) {
        int gg = batch[n];
        if (gg != cur) {
            atomicAdd(&psums[(size_t)cur * 64 + lane], run);
            if (lane == 0) atomicAdd(&pcnt[cur], (float)crun);
            run = 0.f; crun = 0; cur = gg;
        }
        float v = fmaxf(z[(size_t)n * 64 + lane] * sc + sh, 0.f);
        run += v; crun++;
    }
    atomicAdd(&psums[(size_t)cur * 64 + lane], run);
    if (lane == 0) atomicAdd(&pcnt[cur], (float)crun);
}

// ---------- FF branch + fusion head ----------
__global__ void k_head(const float* __restrict__ sigma, const float* __restrict__ Wf1,
                       const float* __restrict__ bf1, const float* __restrict__ Wf2,
                       const float* __restrict__ bf2, const float* __restrict__ Wfu,
                       const float* __restrict__ bfu, const float* __restrict__ sums,
                       const float* __restrict__ cnt, float* __restrict__ out) {
    int g = blockIdx.x;
    int t = threadIdx.x;  // 128 threads
    __shared__ float srow[64], f1[128], f2[64];
    if (t < 64) srow[t] = sigma[(size_t)g * 64 + t];
    __syncthreads();
    {
        float acc = bf1[t];
        for (int s = 0; s < 64; ++s) acc += srow[s] * Wf1[s * 128 + t];
        f1[t] = fmaxf(acc, 0.f);
    }
    __syncthreads();
    if (t < 64) {
        float a2 = bf2[t];
        for (int k = 0; k < 128; ++k) a2 += f1[k] * Wf2[k * 64 + t];
        f2[t] = fmaxf(a2, 0.f);
    }
    __syncthreads();
    if (t < 64) {
        float inv    = 1.0f / fmaxf(cnt[g], 1.0f);
        float pooled = sums[(size_t)g * 64 + t] * inv;
        float contrib = pooled * Wfu[t] + f2[t] * Wfu[64 + t];
#pragma unroll
        for (int o = 32; o > 0; o >>= 1) contrib += __shfl_down(contrib, o);
        if (t == 0) out[g] = contrib + bfu[0];
    }
}

extern "C" void kernel_launch(void* const* d_in, const int* in_sizes, int n_in,
                              void* d_out, int out_size, void* d_ws, size_t ws_size,
                              hipStream_t stream) {
    const float* x     = (const float*)d_in[0];
    const int*   ei    = (const int*)d_in[1];
    const int*   batch = (const int*)d_in[2];
    const float* sigma = (const float*)d_in[3];
    const float* W1 = (const float*)d_in[4];  const float* b1 = (const float*)d_in[5];
    const float* g1 = (const float*)d_in[6];  const float* be1 = (const float*)d_in[7];
    const float* W2 = (const float*)d_in[8];  const float* b2 = (const float*)d_in[9];
    const float* g2 = (const float*)d_in[10]; const float* be2 = (const float*)d_in[11];
    const float* W3 = (const float*)d_in[12]; const float* b3 = (const float*)d_in[13];
    const float* g3 = (const float*)d_in[14]; const float* be3 = (const float*)d_in[15];
    const float* Wf1 = (const float*)d_in[16]; const float* bf1 = (const float*)d_in[17];
    const float* Wf2 = (const float*)d_in[18]; const float* bf2 = (const float*)d_in[19];
    const float* Wfu = (const float*)d_in[20]; const float* bfu = (const float*)d_in[21];

    const int N = in_sizes[0] / 128;
    const int E = in_sizes[1] / 2;
    const int G = in_sizes[3] / 64;
    const int* src = ei;
    const int* dst = ei + E;

    float* ws   = (float*)d_ws;
    float* bufA = ws;                         // z2 / z3 (f32)
    float* bufB = bufA + (size_t)N * 64;      // z1 / h2
    float* bufC = bufB + (size_t)N * 64;      // h1
    __hip_bfloat16* hsb = (__hip_bfloat16*)(bufC + (size_t)N * 64);  // bf16 hs table (N*64)
    float* dis  = (float*)(hsb + (size_t)N * 64);
    int2*  rc      = (int2*)(dis + N);
    int*   row_ptr = (int*)(rc + N);
    int*   bsum    = row_ptr + N;
    int*   csr_src = bsum + 1024;
    // ---- contiguous zero region ----
    int*   cnt     = csr_src + E;
    int*   cursor  = cnt + N;
    float* stats1  = (float*)(cursor + N);
    float* stats2  = stats1 + 128;
    float* stats3  = stats2 + 128;
    float* psums   = stats3 + 128;
    float* pcnt    = psums + (size_t)G * 64;
    size_t zero_bytes = ((char*)(pcnt + G)) - ((char*)cnt);

    const float invN = 1.0f / (float)N;
    const int totNH  = N * 64;
    const int tot4   = totNH / 4;
    const int nb     = (N + 255) / 256;

    hipMemsetAsync(cnt, 0, zero_bytes, stream);

    // ---- CSR build + degrees ----
    k_hist<<<(E + 255) / 256, 256, 0, stream>>>(dst, cnt, E);
    k_scanA<<<nb, 256, 0, stream>>>(cnt, bsum, N);
    k_scanB<<<1, 1024, 0, stream>>>(bsum, nb);
    k_scanC<<<nb, 256, 0, stream>>>(cnt, bsum, row_ptr, rc, dis, N);
    k_fill<<<(E + 255) / 256, 256, 0, stream>>>(src, dst, row_ptr, cursor, csr_src, E);

    // ---- layer 1 ----
    k_gemm_big<128><<<2048, 256, 0, stream>>>(x, W1, dis, hsb, N);
    k_gather8<<<2048, 256, 0, stream>>>(rc, csr_src, dis, hsb, b1, bufB, stats1, N);
    k_norm4<<<(tot4 + 255) / 256, 256, 0, stream>>>(bufB, stats1, g1, be1, nullptr, bufC, invN, tot4);

    // ---- layer 2 (residual = bufC = h1) ----
    k_gemm_big<64><<<2048, 256, 0, stream>>>(bufC, W2, dis, hsb, N);
    k_gather8<<<2048, 256, 0, stream>>>(rc, csr_src, dis, hsb, b2, bufA, stats2, N);
    k_norm4<<<(tot4 + 255) / 256, 256, 0, stream>>>(bufA, stats2, g2, be2, bufC, bufB, invN, tot4); // h2 -> bufB

    // ---- layer 3 ----
    k_gemm_big<64><<<2048, 256, 0, stream>>>(bufB, W3, dis, hsb, N);
    k_gather8<<<2048, 256, 0, stream>>>(rc, csr_src, dis, hsb, b3, bufA, stats3, N);

    // ---- fused normalize + relu + pool ----
    {
        const int waves = 8192;
        int per = (N + waves - 1) / waves;
        k_norm_pool<<<2048, 256, 0, stream>>>(bufA, stats3, g3, be3, batch, psums, pcnt, invN, N, per);
    }

    // ---- head ----
    k_head<<<G, 128, 0, stream>>>(sigma, Wf1, bf1, Wf2, bf2, Wfu, bfu, psums, pcnt, (float*)d_out);
}

// Round 8
// 437.402 us; speedup vs baseline: 1.2031x; 1.0430x over previous
//
#include <hip/hip_runtime.h>
#include <hip/hip_bf16.h>

__device__ __forceinline__ float b2f(unsigned short u) {
    union { unsigned int i; float f; } t; t.i = ((unsigned int)u) << 16; return t.f;
}

// ---------- CSR build ----------
__global__ void k_hist(const int* __restrict__ dst, int* __restrict__ cnt, int E) {
    int e = blockIdx.x * blockDim.x + threadIdx.x;
    if (e < E) atomicAdd(&cnt[dst[e]], 1);
}

__global__ void k_scanA(const int* __restrict__ cnt, int* __restrict__ bsum, int N) {
    __shared__ int sh[256];
    int i = blockIdx.x * 256 + threadIdx.x;
    sh[threadIdx.x] = (i < N) ? cnt[i] : 0;
    __syncthreads();
    for (int off = 128; off > 0; off >>= 1) {
        if (threadIdx.x < off) sh[threadIdx.x] += sh[threadIdx.x + off];
        __syncthreads();
    }
    if (threadIdx.x == 0) bsum[blockIdx.x] = sh[0];
}

__global__ void k_scanB(int* __restrict__ bsum, int nb) {
    __shared__ int sh[1024];
    int t = threadIdx.x;
    sh[t] = (t < nb) ? bsum[t] : 0;
    __syncthreads();
    for (int off = 1; off < 1024; off <<= 1) {
        int v = (t >= off) ? sh[t - off] : 0;
        __syncthreads();
        sh[t] += v;
        __syncthreads();
    }
    if (t < nb) bsum[t] = (t == 0) ? 0 : sh[t - 1];
}

// local scan + write row_ptr, packed (start,cnt,dis_bits,0), and dis
__global__ void k_scanC(const int* __restrict__ cnt, const int* __restrict__ boff,
                        int* __restrict__ row_ptr, int4* __restrict__ rc4,
                        float* __restrict__ dis, int N) {
    __shared__ int sh[256];
    int i = blockIdx.x * 256 + threadIdx.x;
    int v = (i < N) ? cnt[i] : 0;
    sh[threadIdx.x] = v;
    __syncthreads();
    for (int off = 1; off < 256; off <<= 1) {
        int u = (threadIdx.x >= off) ? sh[threadIdx.x - off] : 0;
        __syncthreads();
        sh[threadIdx.x] += u;
        __syncthreads();
    }
    if (i < N) {
        int start = sh[threadIdx.x] - v + boff[blockIdx.x];
        float d = rsqrtf((float)v + 1.0f);
        row_ptr[i] = start;
        rc4[i] = make_int4(start, v, __float_as_int(d), 0);
        dis[i] = d;
    }
}

__global__ void k_fill(const int* __restrict__ src, const int* __restrict__ dst,
                       const int* __restrict__ row_ptr, int* __restrict__ cursor,
                       int* __restrict__ csr_src, int E) {
    int e = blockIdx.x * blockDim.x + threadIdx.x;
    if (e < E) {
        int d = dst[e];
        int pos = row_ptr[d] + atomicAdd(&cursor[d], 1);
        csr_src[pos] = src[e];
    }
}

// ---------- row-looped GEMM: out_bf16[N][64] = (in[N][K] @ W[K][64]) * dis[row] ----------
template <int K>
__global__ void __launch_bounds__(256) k_gemm_big(const float* __restrict__ in,
                                                  const float* __restrict__ W,
                                                  const float* __restrict__ dis,
                                                  __hip_bfloat16* __restrict__ out, int N) {
    __shared__ float Wl[K * 64];
    for (int i = threadIdx.x; i < K * 16; i += 256)
        ((float4*)Wl)[i] = ((const float4*)W)[i];
    __syncthreads();
    int lane = threadIdx.x & 63;
    int wid  = blockIdx.x * 4 + (threadIdx.x >> 6);
    int nw   = gridDim.x * 4;
    int ngrp = (N + 3) >> 2;
    for (int g = wid; g < ngrp; g += nw) {
        int base = g * 4;
        int r1 = min(base + 1, N - 1), r2 = min(base + 2, N - 1), r3 = min(base + 3, N - 1);
        const float4* p0 = (const float4*)(in + (size_t)base * K);
        const float4* p1 = (const float4*)(in + (size_t)r1 * K);
        const float4* p2 = (const float4*)(in + (size_t)r2 * K);
        const float4* p3 = (const float4*)(in + (size_t)r3 * K);
        float acc0 = 0.f, acc1 = 0.f, acc2 = 0.f, acc3 = 0.f;
#pragma unroll 4
        for (int kg = 0; kg < K / 4; ++kg) {
            float4 a0 = p0[kg], a1 = p1[kg], a2 = p2[kg], a3 = p3[kg];
            int k = kg * 4;
            float w0 = Wl[(k + 0) * 64 + lane];
            float w1 = Wl[(k + 1) * 64 + lane];
            float w2 = Wl[(k + 2) * 64 + lane];
            float w3 = Wl[(k + 3) * 64 + lane];
            acc0 = fmaf(a0.w, w3, fmaf(a0.z, w2, fmaf(a0.y, w1, fmaf(a0.x, w0, acc0))));
            acc1 = fmaf(a1.w, w3, fmaf(a1.z, w2, fmaf(a1.y, w1, fmaf(a1.x, w0, acc1))));
            acc2 = fmaf(a2.w, w3, fmaf(a2.z, w2, fmaf(a2.y, w1, fmaf(a2.x, w0, acc2))));
            acc3 = fmaf(a3.w, w3, fmaf(a3.z, w2, fmaf(a3.y, w1, fmaf(a3.x, w0, acc3))));
        }
        out[(size_t)base * 64 + lane] = __float2bfloat16(acc0 * dis[base]);
        if (base + 1 < N) out[(size_t)(base + 1) * 64 + lane] = __float2bfloat16(acc1 * dis[r1]);
        if (base + 2 < N) out[(size_t)(base + 2) * 64 + lane] = __float2bfloat16(acc2 * dis[r2]);
        if (base + 3 < N) out[(size_t)(base + 3) * 64 + lane] = __float2bfloat16(acc3 * dis[r3]);
    }
}

// ---------- pair-row oct-gather: 2 dst rows per wave-iteration, all loads issued upfront ----------
// z[n] = dis[n] * (sum_{s in in(n)} hs[s] + hs[n]) + b ;  accumulate BN stats (f32).
__global__ void __launch_bounds__(256) k_gather8v2(const int4* __restrict__ rc4,
                                                   const int* __restrict__ csr_src,
                                                   const __hip_bfloat16* __restrict__ hs,
                                                   const float* __restrict__ b,
                                                   float* __restrict__ z,
                                                   float* __restrict__ stats, int N) {
    const unsigned short* hsu = (const unsigned short*)hs;
    int tid  = threadIdx.x;
    int lane = tid & 63;
    int w    = tid >> 6;       // wave 0..3
    int grp  = lane >> 3;      // which of 8 src rows
    int sub  = lane & 7;       // 16B segment (8 feats) within 128B row
    float vb[8];
    *(float4*)&vb[0] = *(const float4*)(b + sub * 8);
    *(float4*)&vb[4] = *(const float4*)(b + sub * 8 + 4);
    float ps[8] = {0,0,0,0,0,0,0,0}, pq[8] = {0,0,0,0,0,0,0,0};
    int wid = blockIdx.x * 4 + w;
    int nw  = gridDim.x * 4;
    const float4 zero4 = {0.f, 0.f, 0.f, 0.f};
    for (int base = wid * 2; base < N; base += nw * 2) {
        int nA = base;
        int nB = base + 1;
        bool hasB = (nB < N);
        int4 ra = rc4[nA];
        int4 rb = hasB ? rc4[nB] : make_int4(0, 0, 0, 0);
        int startA = ra.x, cA = ra.y; float dA = __int_as_float(ra.z);
        int startB = rb.x, cB = rb.y; float dB = __int_as_float(rb.z);
        // ---- issue all index loads (exec-masked) ----
        int sA0 = -1, sA1 = -1, sA2 = -1, sB0 = -1, sB1 = -1, sB2 = -1;
        if (grp      < cA) sA0 = csr_src[startA + grp];
        if (8 + grp  < cA) sA1 = csr_src[startA + 8 + grp];
        if (16 + grp < cA) sA2 = csr_src[startA + 16 + grp];
        if (grp      < cB) sB0 = csr_src[startB + grp];
        if (8 + grp  < cB) sB1 = csr_src[startB + 8 + grp];
        if (16 + grp < cB) sB2 = csr_src[startB + 16 + grp];
        // ---- issue all gathers before touching any result ----
        float4 rA0 = zero4, rA1 = zero4, rA2 = zero4;
        float4 rB0 = zero4, rB1 = zero4, rB2 = zero4;
        if (sA0 >= 0) rA0 = *(const float4*)(hsu + (size_t)sA0 * 64 + sub * 8);
        if (sA1 >= 0) rA1 = *(const float4*)(hsu + (size_t)sA1 * 64 + sub * 8);
        if (sA2 >= 0) rA2 = *(const float4*)(hsu + (size_t)sA2 * 64 + sub * 8);
        if (sB0 >= 0) rB0 = *(const float4*)(hsu + (size_t)sB0 * 64 + sub * 8);
        if (sB1 >= 0) rB1 = *(const float4*)(hsu + (size_t)sB1 * 64 + sub * 8);
        if (sB2 >= 0) rB2 = *(const float4*)(hsu + (size_t)sB2 * 64 + sub * 8);
        float4 selfA = *(const float4*)(hsu + (size_t)nA * 64 + sub * 8);
        float4 selfB = hasB ? *(const float4*)(hsu + (size_t)nB * 64 + sub * 8) : zero4;
        // ---- convert + accumulate ----
        float accA[8], accB[8];
        {
            const unsigned short* uA0 = (const unsigned short*)&rA0;
            const unsigned short* uA1 = (const unsigned short*)&rA1;
            const unsigned short* uA2 = (const unsigned short*)&rA2;
            const unsigned short* uB0 = (const unsigned short*)&rB0;
            const unsigned short* uB1 = (const unsigned short*)&rB1;
            const unsigned short* uB2 = (const unsigned short*)&rB2;
#pragma unroll
            for (int i = 0; i < 8; ++i) {
                accA[i] = b2f(uA0[i]) + b2f(uA1[i]) + b2f(uA2[i]);
                accB[i] = b2f(uB0[i]) + b2f(uB1[i]) + b2f(uB2[i]);
            }
        }
        // ---- rare tail: degree > 24 ----
        for (int j = 24; j + grp < cA; j += 8) {
            int s = csr_src[startA + j + grp];
            float4 raw = *(const float4*)(hsu + (size_t)s * 64 + sub * 8);
            const unsigned short* us = (const unsigned short*)&raw;
#pragma unroll
            for (int i = 0; i < 8; ++i) accA[i] += b2f(us[i]);
        }
        for (int j = 24; j + grp < cB; j += 8) {
            int s = csr_src[startB + j + grp];
            float4 raw = *(const float4*)(hsu + (size_t)s * 64 + sub * 8);
            const unsigned short* us = (const unsigned short*)&raw;
#pragma unroll
            for (int i = 0; i < 8; ++i) accB[i] += b2f(us[i]);
        }
        // ---- interleaved reduce over the 8 groups (lane bits 3,4,5) ----
#pragma unroll
        for (int i = 0; i < 8; ++i) { accA[i] += __shfl_xor(accA[i], 8);  accB[i] += __shfl_xor(accB[i], 8); }
#pragma unroll
        for (int i = 0; i < 8; ++i) { accA[i] += __shfl_xor(accA[i], 16); accB[i] += __shfl_xor(accB[i], 16); }
#pragma unroll
        for (int i = 0; i < 8; ++i) { accA[i] += __shfl_xor(accA[i], 32); accB[i] += __shfl_xor(accB[i], 32); }
        if (grp == 0) {
            const unsigned short* suA = (const unsigned short*)&selfA;
            float v[8];
#pragma unroll
            for (int i = 0; i < 8; ++i) {
                v[i] = (accA[i] + b2f(suA[i])) * dA + vb[i];
                ps[i] += v[i];
                pq[i] += v[i] * v[i];
            }
            *(float4*)(z + (size_t)nA * 64 + sub * 8)     = *(float4*)&v[0];
            *(float4*)(z + (size_t)nA * 64 + sub * 8 + 4) = *(float4*)&v[4];
            if (hasB) {
                const unsigned short* suB = (const unsigned short*)&selfB;
#pragma unroll
                for (int i = 0; i < 8; ++i) {
                    v[i] = (accB[i] + b2f(suB[i])) * dB + vb[i];
                    ps[i] += v[i];
                    pq[i] += v[i] * v[i];
                }
                *(float4*)(z + (size_t)nB * 64 + sub * 8)     = *(float4*)&v[0];
                *(float4*)(z + (size_t)nB * 64 + sub * 8 + 4) = *(float4*)&v[4];
            }
        }
    }
    __shared__ float ssum[4][64], ssq[4][64];
    if (grp == 0) {
        *(float4*)&ssum[w][sub * 8]     = *(float4*)&ps[0];
        *(float4*)&ssum[w][sub * 8 + 4] = *(float4*)&ps[4];
        *(float4*)&ssq[w][sub * 8]      = *(float4*)&pq[0];
        *(float4*)&ssq[w][sub * 8 + 4]  = *(float4*)&pq[4];
    }
    __syncthreads();
    if (tid < 64) {
        float s = ssum[0][tid] + ssum[1][tid] + ssum[2][tid] + ssum[3][tid];
        float q = ssq[0][tid] + ssq[1][tid] + ssq[2][tid] + ssq[3][tid];
        atomicAdd(&stats[tid], s);
        atomicAdd(&stats[64 + tid], q);
    }
}

// ---------- normalize (inline BN finalize) + (residual) + relu, float4 ----------
__global__ void k_norm4(const float* __restrict__ z, const float* __restrict__ stats,
                        const float* __restrict__ g, const float* __restrict__ be,
                        const float* __restrict__ res, float* __restrict__ out,
                        float invN, int total4) {
    int i = blockIdx.x * blockDim.x + threadIdx.x;
    if (i >= total4) return;
    int cb = (i & 15) * 4;
    float4 zv = ((const float4*)z)[i];
    float v[4] = {zv.x, zv.y, zv.z, zv.w};
#pragma unroll
    for (int k = 0; k < 4; ++k) {
        int c = cb + k;
        float mu  = stats[c] * invN;
        float var = stats[64 + c] * invN - mu * mu;
        float sc  = g[c] * rsqrtf(var + 1e-5f);
        float sh  = be[c] - mu * sc;
        v[k] = v[k] * sc + sh;
    }
    if (res) {
        float4 rv = ((const float4*)res)[i];
        v[0] += rv.x; v[1] += rv.y; v[2] += rv.z; v[3] += rv.w;
    }
    float4 o;
    o.x = fmaxf(v[0], 0.f); o.y = fmaxf(v[1], 0.f);
    o.z = fmaxf(v[2], 0.f); o.w = fmaxf(v[3], 0.f);
    ((float4*)out)[i] = o;
}

// ---------- layer-3 normalize + relu + segmented pool (batch sorted) ----------
__global__ void k_norm_pool(const float* __restrict__ z, const float* __restrict__ stats,
                            const float* __restrict__ g, const float* __restrict__ be,
                            const int* __restrict__ batch, float* __restrict__ psums,
                            float* __restrict__ pcnt, float invN, int N, int per) {
    int lane = threadIdx.x & 63;
    int wave = (blockIdx.x * blockDim.x + threadIdx.x) >> 6;
    int begin = wave * per;
    if (begin >= N) return;
    int end = begin + per; if (end > N) end = N;
    float mu  = stats[lane] * invN;
    float var = stats[64 + lane] * invN - mu * mu;
    float sc  = g[lane] * rsqrtf(var + 1e-5f);
    float sh  = be[lane] - mu * sc;
    int   cur = batch[begin];
    float run = 0.f;
    int   crun = 0;
    for (int n = begin; n < end; ++n) {
        int gg = batch[n];
        if (gg != cur) {
            atomicAdd(&psums[(size_t)cur * 64 + lane], run);
            if (lane == 0) atomicAdd(&pcnt[cur], (float)crun);
            run = 0.f; crun = 0; cur = gg;
        }
        float v = fmaxf(z[(size_t)n * 64 + lane] * sc + sh, 0.f);
        run += v; crun++;
    }
    atomicAdd(&psums[(size_t)cur * 64 + lane], run);
    if (lane == 0) atomicAdd(&pcnt[cur], (float)crun);
}

// ---------- FF branch + fusion head ----------
__global__ void k_head(const float* __restrict__ sigma, const float* __restrict__ Wf1,
                       const float* __restrict__ bf1, const float* __restrict__ Wf2,
                       const float* __restrict__ bf2, const float* __restrict__ Wfu,
                       const float* __restrict__ bfu, const float* __restrict__ sums,
                       const float* __restrict__ cnt, float* __restrict__ out) {
    int g = blockIdx.x;
    int t = threadIdx.x;  // 128 threads
    __shared__ float srow[64], f1[128], f2[64];
    if (t < 64) srow[t] = sigma[(size_t)g * 64 + t];
    __syncthreads();
    {
        float acc = bf1[t];
        for (int s = 0; s < 64; ++s) acc += srow[s] * Wf1[s * 128 + t];
        f1[t] = fmaxf(acc, 0.f);
    }
    __syncthreads();
    if (t < 64) {
        float a2 = bf2[t];
        for (int k = 0; k < 128; ++k) a2 += f1[k] * Wf2[k * 64 + t];
        f2[t] = fmaxf(a2, 0.f);
    }
    __syncthreads();
    if (t < 64) {
        float inv    = 1.0f / fmaxf(cnt[g], 1.0f);
        float pooled = sums[(size_t)g * 64 + t] * inv;
        float contrib = pooled * Wfu[t] + f2[t] * Wfu[64 + t];
#pragma unroll
        for (int o = 32; o > 0; o >>= 1) contrib += __shfl_down(contrib, o);
        if (t == 0) out[g] = contrib + bfu[0];
    }
}

extern "C" void kernel_launch(void* const* d_in, const int* in_sizes, int n_in,
                              void* d_out, int out_size, void* d_ws, size_t ws_size,
                              hipStream_t stream) {
    const float* x     = (const float*)d_in[0];
    const int*   ei    = (const int*)d_in[1];
    const int*   batch = (const int*)d_in[2];
    const float* sigma = (const float*)d_in[3];
    const float* W1 = (const float*)d_in[4];  const float* b1 = (const float*)d_in[5];
    const float* g1 = (const float*)d_in[6];  const float* be1 = (const float*)d_in[7];
    const float* W2 = (const float*)d_in[8];  const float* b2 = (const float*)d_in[9];
    const float* g2 = (const float*)d_in[10]; const float* be2 = (const float*)d_in[11];
    const float* W3 = (const float*)d_in[12]; const float* b3 = (const float*)d_in[13];
    const float* g3 = (const float*)d_in[14]; const float* be3 = (const float*)d_in[15];
    const float* Wf1 = (const float*)d_in[16]; const float* bf1 = (const float*)d_in[17];
    const float* Wf2 = (const float*)d_in[18]; const float* bf2 = (const float*)d_in[19];
    const float* Wfu = (const float*)d_in[20]; const float* bfu = (const float*)d_in[21];

    const int N = in_sizes[0] / 128;
    const int E = in_sizes[1] / 2;
    const int G = in_sizes[3] / 64;
    const int* src = ei;
    const int* dst = ei + E;

    float* ws   = (float*)d_ws;
    float* bufA = ws;                         // z2 / z3 (f32)
    float* bufB = bufA + (size_t)N * 64;      // z1 / h2
    float* bufC = bufB + (size_t)N * 64;      // h1
    __hip_bfloat16* hsb = (__hip_bfloat16*)(bufC + (size_t)N * 64);  // bf16 hs table (N*64)
    float* dis  = (float*)(hsb + (size_t)N * 64);
    int4*  rc4     = (int4*)(dis + N);
    int*   row_ptr = (int*)(rc4 + N);
    int*   bsum    = row_ptr + N;
    int*   csr_src = bsum + 1024;
    // ---- contiguous zero region ----
    int*   cnt     = csr_src + E;
    int*   cursor  = cnt + N;
    float* stats1  = (float*)(cursor + N);
    float* stats2  = stats1 + 128;
    float* stats3  = stats2 + 128;
    float* psums   = stats3 + 128;
    float* pcnt    = psums + (size_t)G * 64;
    size_t zero_bytes = ((char*)(pcnt + G)) - ((char*)cnt);

    const float invN = 1.0f / (float)N;
    const int totNH  = N * 64;
    const int tot4   = totNH / 4;
    const int nb     = (N + 255) / 256;

    hipMemsetAsync(cnt, 0, zero_bytes, stream);

    // ---- CSR build + degrees ----
    k_hist<<<(E + 255) / 256, 256, 0, stream>>>(dst, cnt, E);
    k_scanA<<<nb, 256, 0, stream>>>(cnt, bsum, N);
    k_scanB<<<1, 1024, 0, stream>>>(bsum, nb);
    k_scanC<<<nb, 256, 0, stream>>>(cnt, bsum, row_ptr, rc4, dis, N);
    k_fill<<<(E + 255) / 256, 256, 0, stream>>>(src, dst, row_ptr, cursor, csr_src, E);

    // ---- layer 1 ----
    k_gemm_big<128><<<2048, 256, 0, stream>>>(x, W1, dis, hsb, N);
    k_gather8v2<<<2048, 256, 0, stream>>>(rc4, csr_src, hsb, b1, bufB, stats1, N);
    k_norm4<<<(tot4 + 255) / 256, 256, 0, stream>>>(bufB, stats1, g1, be1, nullptr, bufC, invN, tot4);

    // ---- layer 2 (residual = bufC = h1) ----
    k_gemm_big<64><<<2048, 256, 0, stream>>>(bufC, W2, dis, hsb, N);
    k_gather8v2<<<2048, 256, 0, stream>>>(rc4, csr_src, hsb, b2, bufA, stats2, N);
    k_norm4<<<(tot4 + 255) / 256, 256, 0, stream>>>(bufA, stats2, g2, be2, bufC, bufB, invN, tot4); // h2 -> bufB

    // ---- layer 3 ----
    k_gemm_big<64><<<2048, 256, 0, stream>>>(bufB, W3, dis, hsb, N);
    k_gather8v2<<<2048, 256, 0, stream>>>(rc4, csr_src, hsb, b3, bufA, stats3, N);

    // ---- fused normalize + relu + pool ----
    {
        const int waves = 8192;
        int per = (N + waves - 1) / waves;
        k_norm_pool<<<2048, 256, 0, stream>>>(bufA, stats3, g3, be3, batch, psums, pcnt, invN, N, per);
    }

    // ---- head ----
    k_head<<<G, 128, 0, stream>>>(sigma, Wf1, bf1, Wf2, bf2, Wfu, bfu, psums, pcnt, (float*)d_out);
}